// Round 5
// baseline (1118.056 us; speedup 1.0000x reference)
//
#include <hip/hip_runtime.h>
#include <stdint.h>

#define B_ 64
#define N_ 16
#define T_ 128
#define I_ 256
#define H_ 256
#define G_ 768   // 3*H
#define TC 64    // time chunk

typedef __attribute__((ext_vector_type(8))) short bf8;        // 8 bf16 in 4 VGPRs (MFMA frag)
typedef __attribute__((ext_vector_type(8))) unsigned short u16x8;
typedef __attribute__((ext_vector_type(4))) float f4;

static __device__ __forceinline__ unsigned short f2bf(float f) {
    uint32_t u = __builtin_bit_cast(uint32_t, f);
    u += 0x7fffu + ((u >> 16) & 1u);   // RNE
    return (unsigned short)(u >> 16);
}
static __device__ __forceinline__ float bf2f(unsigned short s) {
    return __builtin_bit_cast(float, ((uint32_t)s) << 16);
}
static __device__ __forceinline__ float sigm(float x) {
    return __builtin_amdgcn_rcpf(1.f + __expf(-x));
}

// ---- ws layout (bytes) ----
#define OFF_WIH   0ull
#define OFF_WHH   6291456ull
#define OFF_BIAS  12582912ull
#define OFF_H32   12632064ull
#define OFF_IH    13680640ull
#define WS_NEEDED (OFF_IH + 100663296ull)

// ---------------- stage 0: convert/shuffle weights ----------------
__global__ __launch_bounds__(256) void prep_kernel(
        const float* __restrict__ wih, const float* __restrict__ whh,
        const float* __restrict__ bih, const float* __restrict__ bhh,
        unsigned char* ws) {
    unsigned short* wih_fr = (unsigned short*)(ws + OFF_WIH);
    unsigned short* whh_fr = (unsigned short*)(ws + OFF_WHH);
    float* bias_f = (float*)(ws + OFF_BIAS);
    int gid = blockIdx.x * blockDim.x + threadIdx.x;
    int nthr = gridDim.x * blockDim.x;

    // fragment order [n][ct(48)][kt(8)][lane(64)][e(8)]
    //   B-frag: col = ct*16 + (lane&15), k = kt*32 + (lane>>4)*8 + e
    for (int o = gid; o < 393216; o += nthr) {
        int lane = o & 63, kt = (o >> 6) & 7, ct = (o >> 9) % 48, n = o / 24576;
        int gcol = ct * 16 + (lane & 15);
        int k0 = kt * 32 + (lane >> 4) * 8;
        const float* s0 = wih + ((size_t)(n * G_ + gcol)) * I_ + k0;
        const float* s1 = whh + ((size_t)(n * G_ + gcol)) * H_ + k0;
        u16x8 v0, v1;
        #pragma unroll
        for (int e = 0; e < 8; e++) { v0[e] = f2bf(s0[e]); v1[e] = f2bf(s1[e]); }
        *(u16x8*)(wih_fr + (size_t)o * 8) = v0;
        *(u16x8*)(whh_fr + (size_t)o * 8) = v1;
    }
    for (int o = gid; o < N_ * G_; o += nthr) {
        int g = o % G_;
        bias_f[o] = bih[o] + (g < 512 ? bhh[o] : 0.f);
    }
}

// ---------------- stage 1: IH = bf16( x @ wih^T + bias_f ) for one T-chunk ----------------
// grid 1024 = (n,b); block 1024 thr / 16 waves; tile 64 rows x 768 cols, K=256.
// Wave w owns 3 col-tiles. ENTIRE B panel (3x8 frags = 96 VGPR) preloaded before the
// kt loop: 24 back-to-back dwordx4 loads amortize L2 latency once per kernel.
// launch_bounds(1024,8): cap 256 regs/wave -> 2 blocks/CU co-resident.
__global__ __launch_bounds__(1024, 8) void ih_gemm(
        const float* __restrict__ x, const unsigned char* __restrict__ wsr,
        unsigned char* ws, int t0) {
    const unsigned short* wih_fr = (const unsigned short*)(wsr + OFF_WIH);
    const float* bias_f = (const float*)(wsr + OFF_BIAS);
    unsigned short* IH = (unsigned short*)(ws + OFF_IH);

    __shared__ __align__(16) unsigned short As[64 * 256];

    int tid = threadIdx.x, lane = tid & 63, w = tid >> 6;
    int n = blockIdx.x >> 6, b = blockIdx.x & 63;
    int c16 = lane & 15, q = lane >> 4, q16 = q * 8;

    // stage A: 64 rows x 256 k (fp32 -> bf16), swizzled
    {
        const float* xb = x + (((size_t)(b * N_ + n)) * T_ + t0) * I_;
        #pragma unroll
        for (int i = 0; i < 2; i++) {
            int chunk = i * 1024 + tid;
            int row = chunk >> 5, kc = chunk & 31;
            const float* s = xb + row * I_ + kc * 8;
            float4 f0 = *(const float4*)s;
            float4 f1 = *(const float4*)(s + 4);
            u16x8 v;
            v[0] = f2bf(f0.x); v[1] = f2bf(f0.y); v[2] = f2bf(f0.z); v[3] = f2bf(f0.w);
            v[4] = f2bf(f1.x); v[5] = f2bf(f1.y); v[6] = f2bf(f1.z); v[7] = f2bf(f1.w);
            int eoff = row * 256 + ((kc * 8) ^ ((row & 7) << 3));
            *(u16x8*)(As + eoff) = v;
        }
    }

    // preload full B panel: wave w owns col-tiles ct = w*3 .. w*3+2
    const unsigned short* bptr = wih_fr + (((size_t)n * 48 + w * 3) * 8) * 64 * 8;
    bf8 bfr[3][8];
    #pragma unroll
    for (int c = 0; c < 3; c++)
        #pragma unroll
        for (int kt = 0; kt < 8; kt++)
            bfr[c][kt] = *(const bf8*)(bptr + (((size_t)c * 8 + kt) * 64 + lane) * 8);

    __syncthreads();

    f4 acc[4][3];
    f4 zf = {0.f, 0.f, 0.f, 0.f};
    #pragma unroll
    for (int rt = 0; rt < 4; rt++)
        #pragma unroll
        for (int c = 0; c < 3; c++) acc[rt][c] = zf;

    #pragma unroll
    for (int kt = 0; kt < 8; kt++) {
        bf8 a[4];
        #pragma unroll
        for (int rt = 0; rt < 4; rt++) {
            int ar = rt * 16 + c16;
            a[rt] = *(const bf8*)(As + ar * 256 + ((kt * 32 + q16) ^ ((ar & 7) << 3)));
        }
        #pragma unroll
        for (int c = 0; c < 3; c++)
            #pragma unroll
            for (int rt = 0; rt < 4; rt++)
                acc[rt][c] = __builtin_amdgcn_mfma_f32_16x16x32_bf16(a[rt], bfr[c][kt], acc[rt][c], 0, 0, 0);
    }

    // epilogue: +bias, store bf16. D: col = lane&15, row = q*4 + r (within 16-tile)
    size_t obase = (size_t)(b * N_ + n) * TC;
    #pragma unroll
    for (int c = 0; c < 3; c++) {
        int g = (w * 3 + c) * 16 + c16;
        float bias = bias_f[n * G_ + g];
        #pragma unroll
        for (int rt = 0; rt < 4; rt++) {
            #pragma unroll
            for (int r = 0; r < 4; r++) {
                int trow = rt * 16 + q * 4 + r;
                IH[(obase + trow) * G_ + g] = f2bf(acc[rt][c][r] + bias);
            }
        }
    }
}

// ---------------- stage 2: sequential GRU scan (unchanged) ----------------
__global__ __launch_bounds__(512, 2) void gru_scan(
        const unsigned char* __restrict__ wsr, unsigned char* ws,
        const float* __restrict__ bhh, float* __restrict__ out,
        int chunk, int t0) {
    const unsigned short* IH = (const unsigned short*)(wsr + OFF_IH);
    const unsigned short* whh_fr = (const unsigned short*)(wsr + OFF_WHH);
    float* h32ws = (float*)(ws + OFF_H32);

    __shared__ __align__(16) unsigned short hbf[2][4][272];

    int tid = threadIdx.x, lane = tid & 63, w = tid >> 6;
    int n = blockIdx.x & 15, rg = blockIdx.x >> 4;

    int c16 = lane & 15;
    int q = lane >> 4;
    int hrow = c16 >> 2;
    int q16 = q * 8;
    int brow = rg * 4 + q;

    bf8 wf[3][2][8];
    #pragma unroll
    for (int g = 0; g < 3; g++)
        #pragma unroll
        for (int u = 0; u < 2; u++) {
            int ct = g * 16 + w * 2 + u;
            #pragma unroll
            for (int kt = 0; kt < 8; kt++)
                wf[g][u][kt] = *(const bf8*)(whh_fr + ((((size_t)n * 48 + ct) * 8 + kt) * 64 + lane) * 8);
        }

    int colb = w * 32 + c16;
    float bn0 = bhh[n * G_ + 512 + colb];
    float bn1 = bhh[n * G_ + 512 + colb + 16];
    float h0 = 0.f, h1 = 0.f;
    if (chunk) {
        const float* hp = h32ws + ((size_t)brow * N_ + n) * H_ + colb;
        h0 = hp[0]; h1 = hp[16];
    }
    hbf[0][q][colb] = f2bf(h0);
    hbf[0][q][colb + 16] = f2bf(h1);

    const unsigned short* ihp = IH + ((size_t)(brow * N_ + n) * TC) * G_ + colb;

    unsigned short c_r0 = ihp[0],   c_r1 = ihp[16];
    unsigned short c_z0 = ihp[256], c_z1 = ihp[272];
    unsigned short c_n0 = ihp[512], c_n1 = ihp[528];
    ihp += G_;

    f4 zf = {0.f, 0.f, 0.f, 0.f};
    __syncthreads();

    #pragma unroll 1
    for (int t = 0; t < TC; t++) {
        const unsigned short* pp = (t + 1 < TC) ? ihp : (ihp - G_);
        unsigned short n_r0 = pp[0],   n_r1 = pp[16];
        unsigned short n_z0 = pp[256], n_z1 = pp[272];
        unsigned short n_n0 = pp[512], n_n1 = pp[528];
        ihp += G_;

        const unsigned short* hb = &hbf[t & 1][0][0];
        f4 acc[3][2];
        #pragma unroll
        for (int g = 0; g < 3; g++)
            #pragma unroll
            for (int u = 0; u < 2; u++) acc[g][u] = zf;
        #pragma unroll
        for (int kt = 0; kt < 8; kt++) {
            bf8 a = *(const bf8*)(hb + hrow * 272 + kt * 32 + q16);
            #pragma unroll
            for (int g = 0; g < 3; g++)
                #pragma unroll
                for (int u = 0; u < 2; u++)
                    acc[g][u] = __builtin_amdgcn_mfma_f32_16x16x32_bf16(a, wf[g][u][kt], acc[g][u], 0, 0, 0);
        }

        float xr0 = bf2f(c_r0) + acc[0][0][0];
        float xz0 = bf2f(c_z0) + acc[1][0][0];
        float rr0 = sigm(xr0), zz0 = sigm(xz0);
        float pre0 = bf2f(c_n0) + rr0 * (acc[2][0][0] + bn0);
        float e20 = __expf(2.f * pre0);
        float nv0 = 1.f - 2.f * __builtin_amdgcn_rcpf(e20 + 1.f);
        float hn0 = nv0 + zz0 * (h0 - nv0);

        float xr1 = bf2f(c_r1) + acc[0][1][0];
        float xz1 = bf2f(c_z1) + acc[1][1][0];
        float rr1 = sigm(xr1), zz1 = sigm(xz1);
        float pre1 = bf2f(c_n1) + rr1 * (acc[2][1][0] + bn1);
        float e21 = __expf(2.f * pre1);
        float nv1 = 1.f - 2.f * __builtin_amdgcn_rcpf(e21 + 1.f);
        float hn1 = nv1 + zz1 * (h1 - nv1);

        h0 = hn0; h1 = hn1;

        unsigned short* hw = &hbf[(t & 1) ^ 1][q][colb];
        hw[0] = f2bf(hn0);
        hw[16] = f2bf(hn1);

        float* op = out + ((size_t)(brow * N_ + n) * T_ + (t0 + t)) * H_ + colb;
        op[0] = hn0;
        op[16] = hn1;

        c_r0 = n_r0; c_r1 = n_r1;
        c_z0 = n_z0; c_z1 = n_z1;
        c_n0 = n_n0; c_n1 = n_n1;

        __syncthreads();
    }

    float* hp = h32ws + ((size_t)brow * N_ + n) * H_ + colb;
    hp[0] = h0;
    hp[16] = h1;
}

extern "C" void kernel_launch(void* const* d_in, const int* in_sizes, int n_in,
                              void* d_out, int out_size, void* d_ws, size_t ws_size,
                              hipStream_t stream) {
    const float* x   = (const float*)d_in[0];
    const float* wih = (const float*)d_in[1];
    const float* whh = (const float*)d_in[2];
    const float* bih = (const float*)d_in[3];
    const float* bhh = (const float*)d_in[4];
    float* out = (float*)d_out;
    unsigned char* ws = (unsigned char*)d_ws;

    if (ws_size < WS_NEEDED) return;

    prep_kernel<<<1024, 256, 0, stream>>>(wih, whh, bih, bhh, ws);
    for (int chunk = 0; chunk < 2; chunk++) {
        int t0 = chunk * TC;
        ih_gemm<<<dim3(1024), 1024, 0, stream>>>(x, ws, ws, t0);
        gru_scan<<<dim3(256), 512, 0, stream>>>(ws, ws, bhh, out, chunk, t0);
    }
}

// Round 6
// 280.053 us; speedup vs baseline: 3.9923x; 3.9923x over previous
//
#include <hip/hip_runtime.h>
#include <stdint.h>

#define B_ 64
#define N_ 16
#define T_ 128
#define I_ 256
#define H_ 256
#define G_ 768   // 3*H
#define TC 64    // time chunk

typedef __attribute__((ext_vector_type(8))) short bf8;        // 8 bf16 in 4 VGPRs (MFMA frag)
typedef __attribute__((ext_vector_type(8))) unsigned short u16x8;
typedef __attribute__((ext_vector_type(4))) float f4;

static __device__ __forceinline__ unsigned short f2bf(float f) {
    uint32_t u = __builtin_bit_cast(uint32_t, f);
    u += 0x7fffu + ((u >> 16) & 1u);   // RNE
    return (unsigned short)(u >> 16);
}
static __device__ __forceinline__ float bf2f(unsigned short s) {
    return __builtin_bit_cast(float, ((uint32_t)s) << 16);
}
static __device__ __forceinline__ float sigm(float x) {
    return __builtin_amdgcn_rcpf(1.f + __expf(-x));
}

// ---- ws layout (bytes) ----
#define OFF_WIH   0ull
#define OFF_WHH   6291456ull
#define OFF_BIAS  12582912ull
#define OFF_H32   12632064ull
#define OFF_IH    13680640ull
#define WS_NEEDED (OFF_IH + 100663296ull)

// ---------------- stage 0: convert/shuffle weights ----------------
__global__ __launch_bounds__(256) void prep_kernel(
        const float* __restrict__ wih, const float* __restrict__ whh,
        const float* __restrict__ bih, const float* __restrict__ bhh,
        unsigned char* ws) {
    unsigned short* wih_fr = (unsigned short*)(ws + OFF_WIH);
    unsigned short* whh_fr = (unsigned short*)(ws + OFF_WHH);
    float* bias_f = (float*)(ws + OFF_BIAS);
    int gid = blockIdx.x * blockDim.x + threadIdx.x;
    int nthr = gridDim.x * blockDim.x;

    // fragment order [n][ct(48)][kt(8)][lane(64)][e(8)]
    //   B-frag: col = ct*16 + (lane&15), k = kt*32 + (lane>>4)*8 + e
    for (int o = gid; o < 393216; o += nthr) {
        int lane = o & 63, kt = (o >> 6) & 7, ct = (o >> 9) % 48, n = o / 24576;
        int gcol = ct * 16 + (lane & 15);
        int k0 = kt * 32 + (lane >> 4) * 8;
        const float* s0 = wih + ((size_t)(n * G_ + gcol)) * I_ + k0;
        const float* s1 = whh + ((size_t)(n * G_ + gcol)) * H_ + k0;
        u16x8 v0, v1;
        #pragma unroll
        for (int e = 0; e < 8; e++) { v0[e] = f2bf(s0[e]); v1[e] = f2bf(s1[e]); }
        *(u16x8*)(wih_fr + (size_t)o * 8) = v0;
        *(u16x8*)(whh_fr + (size_t)o * 8) = v1;
    }
    for (int o = gid; o < N_ * G_; o += nthr) {
        int g = o % G_;
        bias_f[o] = bih[o] + (g < 512 ? bhh[o] : 0.f);
    }
}

// ---------------- stage 1: IH = bf16( x @ wih^T + bias_f ) for one T-chunk ----------------
// grid 256 = 1 block/CU; block = (n, bq) covering 4 b-tiles of 64 rows x 768 cols.
// XCD-aware map: n = (blk&7)*2 + (blk>>7) -> both blocks of an n-pair share an XCD L2.
// All 4 A-tiles staged up front (128 KB LDS, ONE barrier), then 16 waves run 4
// barrier-free compute iterations; wih[n] B-panel re-read per iter is L2-hot.
__global__ __launch_bounds__(1024, 1) void ih_gemm(
        const float* __restrict__ x, const unsigned char* __restrict__ wsr,
        unsigned char* ws, int t0) {
    const unsigned short* wih_fr = (const unsigned short*)(wsr + OFF_WIH);
    const float* bias_f = (const float*)(wsr + OFF_BIAS);
    unsigned short* IH = (unsigned short*)(ws + OFF_IH);

    __shared__ __align__(16) unsigned short As[4 * 64 * 256];   // 128 KB

    int tid = threadIdx.x, lane = tid & 63, w = tid >> 6;
    int blk = blockIdx.x;
    int n = (blk & 7) * 2 + (blk >> 7);
    int bq = (blk >> 3) & 15;
    int c16 = lane & 15, q = lane >> 4, q16 = q * 8;

    // stage A: 4 tiles x 64 rows x 256 k (fp32 -> bf16), swizzled
    #pragma unroll
    for (int i = 0; i < 4; i++) {
        int b = bq * 4 + i;
        const float* xb = x + (((size_t)(b * N_ + n)) * T_ + t0) * I_;
        #pragma unroll
        for (int j = 0; j < 2; j++) {
            int chunk = j * 1024 + tid;
            int row = chunk >> 5, kc = chunk & 31;
            const float* s = xb + row * I_ + kc * 8;
            float4 f0 = *(const float4*)s;
            float4 f1 = *(const float4*)(s + 4);
            u16x8 v;
            v[0] = f2bf(f0.x); v[1] = f2bf(f0.y); v[2] = f2bf(f0.z); v[3] = f2bf(f0.w);
            v[4] = f2bf(f1.x); v[5] = f2bf(f1.y); v[6] = f2bf(f1.z); v[7] = f2bf(f1.w);
            int eoff = i * 16384 + row * 256 + ((kc * 8) ^ ((row & 7) << 3));
            *(u16x8*)(As + eoff) = v;
        }
    }
    __syncthreads();

    // wave w owns col-tiles ct = w*3 .. w*3+2
    const unsigned short* bptr = wih_fr + (((size_t)n * 48 + w * 3) * 8) * 64 * 8;
    f4 zf = {0.f, 0.f, 0.f, 0.f};

    #pragma unroll 1
    for (int i = 0; i < 4; i++) {
        int b = bq * 4 + i;
        const unsigned short* Ai = As + i * 16384;

        f4 acc[4][3];
        #pragma unroll
        for (int rt = 0; rt < 4; rt++)
            #pragma unroll
            for (int c = 0; c < 3; c++) acc[rt][c] = zf;

        bf8 bc[3], bn[3];
        #pragma unroll
        for (int c = 0; c < 3; c++)
            bc[c] = *(const bf8*)(bptr + (((size_t)c * 8 + 0) * 64 + lane) * 8);

        #pragma unroll 1
        for (int kt = 0; kt < 8; kt++) {
            int ktn = (kt + 1) & 7;
            #pragma unroll
            for (int c = 0; c < 3; c++)
                bn[c] = *(const bf8*)(bptr + (((size_t)c * 8 + ktn) * 64 + lane) * 8);
            bf8 a[4];
            #pragma unroll
            for (int rt = 0; rt < 4; rt++) {
                int ar = rt * 16 + c16;
                a[rt] = *(const bf8*)(Ai + ar * 256 + ((kt * 32 + q16) ^ ((ar & 7) << 3)));
            }
            #pragma unroll
            for (int c = 0; c < 3; c++)
                #pragma unroll
                for (int rt = 0; rt < 4; rt++)
                    acc[rt][c] = __builtin_amdgcn_mfma_f32_16x16x32_bf16(a[rt], bc[c], acc[rt][c], 0, 0, 0);
            #pragma unroll
            for (int c = 0; c < 3; c++) bc[c] = bn[c];
        }

        // epilogue: +bias, store bf16. D: col = lane&15, row = q*4 + r (within 16-tile)
        size_t obase = (size_t)(b * N_ + n) * TC;
        #pragma unroll
        for (int c = 0; c < 3; c++) {
            int g = (w * 3 + c) * 16 + c16;
            float bias = bias_f[n * G_ + g];
            #pragma unroll
            for (int rt = 0; rt < 4; rt++) {
                #pragma unroll
                for (int r = 0; r < 4; r++) {
                    int trow = rt * 16 + q * 4 + r;
                    IH[(obase + trow) * G_ + g] = f2bf(acc[rt][c][r] + bias);
                }
            }
        }
    }
}

// ---------------- stage 2: sequential GRU scan (unchanged) ----------------
__global__ __launch_bounds__(512, 2) void gru_scan(
        const unsigned char* __restrict__ wsr, unsigned char* ws,
        const float* __restrict__ bhh, float* __restrict__ out,
        int chunk, int t0) {
    const unsigned short* IH = (const unsigned short*)(wsr + OFF_IH);
    const unsigned short* whh_fr = (const unsigned short*)(wsr + OFF_WHH);
    float* h32ws = (float*)(ws + OFF_H32);

    __shared__ __align__(16) unsigned short hbf[2][4][272];

    int tid = threadIdx.x, lane = tid & 63, w = tid >> 6;
    int n = blockIdx.x & 15, rg = blockIdx.x >> 4;

    int c16 = lane & 15;
    int q = lane >> 4;
    int hrow = c16 >> 2;
    int q16 = q * 8;
    int brow = rg * 4 + q;

    bf8 wf[3][2][8];
    #pragma unroll
    for (int g = 0; g < 3; g++)
        #pragma unroll
        for (int u = 0; u < 2; u++) {
            int ct = g * 16 + w * 2 + u;
            #pragma unroll
            for (int kt = 0; kt < 8; kt++)
                wf[g][u][kt] = *(const bf8*)(whh_fr + ((((size_t)n * 48 + ct) * 8 + kt) * 64 + lane) * 8);
        }

    int colb = w * 32 + c16;
    float bn0 = bhh[n * G_ + 512 + colb];
    float bn1 = bhh[n * G_ + 512 + colb + 16];
    float h0 = 0.f, h1 = 0.f;
    if (chunk) {
        const float* hp = h32ws + ((size_t)brow * N_ + n) * H_ + colb;
        h0 = hp[0]; h1 = hp[16];
    }
    hbf[0][q][colb] = f2bf(h0);
    hbf[0][q][colb + 16] = f2bf(h1);

    const unsigned short* ihp = IH + ((size_t)(brow * N_ + n) * TC) * G_ + colb;

    unsigned short c_r0 = ihp[0],   c_r1 = ihp[16];
    unsigned short c_z0 = ihp[256], c_z1 = ihp[272];
    unsigned short c_n0 = ihp[512], c_n1 = ihp[528];
    ihp += G_;

    f4 zf = {0.f, 0.f, 0.f, 0.f};
    __syncthreads();

    #pragma unroll 1
    for (int t = 0; t < TC; t++) {
        const unsigned short* pp = (t + 1 < TC) ? ihp : (ihp - G_);
        unsigned short n_r0 = pp[0],   n_r1 = pp[16];
        unsigned short n_z0 = pp[256], n_z1 = pp[272];
        unsigned short n_n0 = pp[512], n_n1 = pp[528];
        ihp += G_;

        const unsigned short* hb = &hbf[t & 1][0][0];
        f4 acc[3][2];
        #pragma unroll
        for (int g = 0; g < 3; g++)
            #pragma unroll
            for (int u = 0; u < 2; u++) acc[g][u] = zf;
        #pragma unroll
        for (int kt = 0; kt < 8; kt++) {
            bf8 a = *(const bf8*)(hb + hrow * 272 + kt * 32 + q16);
            #pragma unroll
            for (int g = 0; g < 3; g++)
                #pragma unroll
                for (int u = 0; u < 2; u++)
                    acc[g][u] = __builtin_amdgcn_mfma_f32_16x16x32_bf16(a, wf[g][u][kt], acc[g][u], 0, 0, 0);
        }

        float xr0 = bf2f(c_r0) + acc[0][0][0];
        float xz0 = bf2f(c_z0) + acc[1][0][0];
        float rr0 = sigm(xr0), zz0 = sigm(xz0);
        float pre0 = bf2f(c_n0) + rr0 * (acc[2][0][0] + bn0);
        float e20 = __expf(2.f * pre0);
        float nv0 = 1.f - 2.f * __builtin_amdgcn_rcpf(e20 + 1.f);
        float hn0 = nv0 + zz0 * (h0 - nv0);

        float xr1 = bf2f(c_r1) + acc[0][1][0];
        float xz1 = bf2f(c_z1) + acc[1][1][0];
        float rr1 = sigm(xr1), zz1 = sigm(xz1);
        float pre1 = bf2f(c_n1) + rr1 * (acc[2][1][0] + bn1);
        float e21 = __expf(2.f * pre1);
        float nv1 = 1.f - 2.f * __builtin_amdgcn_rcpf(e21 + 1.f);
        float hn1 = nv1 + zz1 * (h1 - nv1);

        h0 = hn0; h1 = hn1;

        unsigned short* hw = &hbf[(t & 1) ^ 1][q][colb];
        hw[0] = f2bf(hn0);
        hw[16] = f2bf(hn1);

        float* op = out + ((size_t)(brow * N_ + n) * T_ + (t0 + t)) * H_ + colb;
        op[0] = hn0;
        op[16] = hn1;

        c_r0 = n_r0; c_r1 = n_r1;
        c_z0 = n_z0; c_z1 = n_z1;
        c_n0 = n_n0; c_n1 = n_n1;

        __syncthreads();
    }

    float* hp = h32ws + ((size_t)brow * N_ + n) * H_ + colb;
    hp[0] = h0;
    hp[16] = h1;
}

extern "C" void kernel_launch(void* const* d_in, const int* in_sizes, int n_in,
                              void* d_out, int out_size, void* d_ws, size_t ws_size,
                              hipStream_t stream) {
    const float* x   = (const float*)d_in[0];
    const float* wih = (const float*)d_in[1];
    const float* whh = (const float*)d_in[2];
    const float* bih = (const float*)d_in[3];
    const float* bhh = (const float*)d_in[4];
    float* out = (float*)d_out;
    unsigned char* ws = (unsigned char*)d_ws;

    if (ws_size < WS_NEEDED) return;

    prep_kernel<<<1024, 256, 0, stream>>>(wih, whh, bih, bhh, ws);
    for (int chunk = 0; chunk < 2; chunk++) {
        int t0 = chunk * TC;
        ih_gemm<<<dim3(256), 1024, 0, stream>>>(x, ws, ws, t0);
        gru_scan<<<dim3(256), 512, 0, stream>>>(ws, ws, bhh, out, chunk, t0);
    }
}

// Round 7
// 276.885 us; speedup vs baseline: 4.0380x; 1.0114x over previous
//
#include <hip/hip_runtime.h>
#include <stdint.h>

#define B_ 64
#define N_ 16
#define T_ 128
#define I_ 256
#define H_ 256
#define G_ 768   // 3*H
#define TC 64    // time chunk

typedef __attribute__((ext_vector_type(8))) short bf8;        // 8 bf16 in 4 VGPRs (MFMA frag)
typedef __attribute__((ext_vector_type(8))) unsigned short u16x8;
typedef __attribute__((ext_vector_type(4))) float f4;

static __device__ __forceinline__ unsigned short f2bf(float f) {
    uint32_t u = __builtin_bit_cast(uint32_t, f);
    u += 0x7fffu + ((u >> 16) & 1u);   // RNE
    return (unsigned short)(u >> 16);
}
static __device__ __forceinline__ float bf2f(unsigned short s) {
    return __builtin_bit_cast(float, ((uint32_t)s) << 16);
}
static __device__ __forceinline__ float sigm(float x) {
    return __builtin_amdgcn_rcpf(1.f + __expf(-x));
}

// Barrier that waits ONLY on LDS ops (lgkmcnt) — unlike __syncthreads(), it does
// NOT drain vmcnt, so global prefetch loads / output stores stay in flight across
// the per-step barrier. h-tile ds_writes are visible: lgkmcnt(0) before s_barrier.
static __device__ __forceinline__ void barrier_lds_only() {
    asm volatile("s_waitcnt lgkmcnt(0)\n\ts_barrier" ::: "memory");
}

// ---- ws layout (bytes) ----
#define OFF_WIH   0ull
#define OFF_WHH   6291456ull
#define OFF_BIAS  12582912ull
#define OFF_H32   12632064ull
#define OFF_IH    13680640ull
#define WS_NEEDED (OFF_IH + 100663296ull)

// ---------------- stage 0: convert/shuffle weights ----------------
__global__ __launch_bounds__(256) void prep_kernel(
        const float* __restrict__ wih, const float* __restrict__ whh,
        const float* __restrict__ bih, const float* __restrict__ bhh,
        unsigned char* ws) {
    unsigned short* wih_fr = (unsigned short*)(ws + OFF_WIH);
    unsigned short* whh_fr = (unsigned short*)(ws + OFF_WHH);
    float* bias_f = (float*)(ws + OFF_BIAS);
    int gid = blockIdx.x * blockDim.x + threadIdx.x;
    int nthr = gridDim.x * blockDim.x;

    // fragment order [n][ct(48)][kt(8)][lane(64)][e(8)]
    //   B-frag: col = ct*16 + (lane&15), k = kt*32 + (lane>>4)*8 + e
    for (int o = gid; o < 393216; o += nthr) {
        int lane = o & 63, kt = (o >> 6) & 7, ct = (o >> 9) % 48, n = o / 24576;
        int gcol = ct * 16 + (lane & 15);
        int k0 = kt * 32 + (lane >> 4) * 8;
        const float* s0 = wih + ((size_t)(n * G_ + gcol)) * I_ + k0;
        const float* s1 = whh + ((size_t)(n * G_ + gcol)) * H_ + k0;
        u16x8 v0, v1;
        #pragma unroll
        for (int e = 0; e < 8; e++) { v0[e] = f2bf(s0[e]); v1[e] = f2bf(s1[e]); }
        *(u16x8*)(wih_fr + (size_t)o * 8) = v0;
        *(u16x8*)(whh_fr + (size_t)o * 8) = v1;
    }
    for (int o = gid; o < N_ * G_; o += nthr) {
        int g = o % G_;
        bias_f[o] = bih[o] + (g < 512 ? bhh[o] : 0.f);
    }
}

// ---------------- stage 1: IH = bf16( x @ wih^T + bias_f ) for one T-chunk ----------------
// grid 256 = 1 block/CU; block = (n, bq) covering 4 b-tiles of 64 rows x 768 cols.
// XCD-aware map: n = (blk&7)*2 + (blk>>7) -> both blocks of an n-pair share an XCD L2.
__global__ __launch_bounds__(1024, 1) void ih_gemm(
        const float* __restrict__ x, const unsigned char* __restrict__ wsr,
        unsigned char* ws, int t0) {
    const unsigned short* wih_fr = (const unsigned short*)(wsr + OFF_WIH);
    const float* bias_f = (const float*)(wsr + OFF_BIAS);
    unsigned short* IH = (unsigned short*)(ws + OFF_IH);

    __shared__ __align__(16) unsigned short As[4 * 64 * 256];   // 128 KB

    int tid = threadIdx.x, lane = tid & 63, w = tid >> 6;
    int blk = blockIdx.x;
    int n = (blk & 7) * 2 + (blk >> 7);
    int bq = (blk >> 3) & 15;
    int c16 = lane & 15, q = lane >> 4, q16 = q * 8;

    // stage A: 4 tiles x 64 rows x 256 k (fp32 -> bf16), swizzled
    #pragma unroll
    for (int i = 0; i < 4; i++) {
        int b = bq * 4 + i;
        const float* xb = x + (((size_t)(b * N_ + n)) * T_ + t0) * I_;
        #pragma unroll
        for (int j = 0; j < 2; j++) {
            int chunk = j * 1024 + tid;
            int row = chunk >> 5, kc = chunk & 31;
            const float* s = xb + row * I_ + kc * 8;
            float4 f0 = *(const float4*)s;
            float4 f1 = *(const float4*)(s + 4);
            u16x8 v;
            v[0] = f2bf(f0.x); v[1] = f2bf(f0.y); v[2] = f2bf(f0.z); v[3] = f2bf(f0.w);
            v[4] = f2bf(f1.x); v[5] = f2bf(f1.y); v[6] = f2bf(f1.z); v[7] = f2bf(f1.w);
            int eoff = i * 16384 + row * 256 + ((kc * 8) ^ ((row & 7) << 3));
            *(u16x8*)(As + eoff) = v;
        }
    }
    __syncthreads();

    // wave w owns col-tiles ct = w*3 .. w*3+2
    const unsigned short* bptr = wih_fr + (((size_t)n * 48 + w * 3) * 8) * 64 * 8;
    f4 zf = {0.f, 0.f, 0.f, 0.f};

    #pragma unroll 1
    for (int i = 0; i < 4; i++) {
        int b = bq * 4 + i;
        const unsigned short* Ai = As + i * 16384;

        f4 acc[4][3];
        #pragma unroll
        for (int rt = 0; rt < 4; rt++)
            #pragma unroll
            for (int c = 0; c < 3; c++) acc[rt][c] = zf;

        bf8 bc[3], bn[3];
        #pragma unroll
        for (int c = 0; c < 3; c++)
            bc[c] = *(const bf8*)(bptr + (((size_t)c * 8 + 0) * 64 + lane) * 8);

        #pragma unroll 1
        for (int kt = 0; kt < 8; kt++) {
            int ktn = (kt + 1) & 7;
            #pragma unroll
            for (int c = 0; c < 3; c++)
                bn[c] = *(const bf8*)(bptr + (((size_t)c * 8 + ktn) * 64 + lane) * 8);
            bf8 a[4];
            #pragma unroll
            for (int rt = 0; rt < 4; rt++) {
                int ar = rt * 16 + c16;
                a[rt] = *(const bf8*)(Ai + ar * 256 + ((kt * 32 + q16) ^ ((ar & 7) << 3)));
            }
            #pragma unroll
            for (int c = 0; c < 3; c++)
                #pragma unroll
                for (int rt = 0; rt < 4; rt++)
                    acc[rt][c] = __builtin_amdgcn_mfma_f32_16x16x32_bf16(a[rt], bc[c], acc[rt][c], 0, 0, 0);
            #pragma unroll
            for (int c = 0; c < 3; c++) bc[c] = bn[c];
        }

        // epilogue: +bias, store bf16. D: col = lane&15, row = q*4 + r (within 16-tile)
        size_t obase = (size_t)(b * N_ + n) * TC;
        #pragma unroll
        for (int c = 0; c < 3; c++) {
            int g = (w * 3 + c) * 16 + c16;
            float bias = bias_f[n * G_ + g];
            #pragma unroll
            for (int rt = 0; rt < 4; rt++) {
                #pragma unroll
                for (int r = 0; r < 4; r++) {
                    int trow = rt * 16 + q * 4 + r;
                    IH[(obase + trow) * G_ + g] = f2bf(acc[rt][c][r] + bias);
                }
            }
        }
    }
}

// ---------------- stage 2: sequential GRU scan ----------------
// Change vs R6: per-step barrier no longer drains vmcnt -> IH prefetch and out[]
// stores stay in flight across steps.
__global__ __launch_bounds__(512, 2) void gru_scan(
        const unsigned char* __restrict__ wsr, unsigned char* ws,
        const float* __restrict__ bhh, float* __restrict__ out,
        int chunk, int t0) {
    const unsigned short* IH = (const unsigned short*)(wsr + OFF_IH);
    const unsigned short* whh_fr = (const unsigned short*)(wsr + OFF_WHH);
    float* h32ws = (float*)(ws + OFF_H32);

    __shared__ __align__(16) unsigned short hbf[2][4][272];

    int tid = threadIdx.x, lane = tid & 63, w = tid >> 6;
    int n = blockIdx.x & 15, rg = blockIdx.x >> 4;

    int c16 = lane & 15;
    int q = lane >> 4;
    int hrow = c16 >> 2;
    int q16 = q * 8;
    int brow = rg * 4 + q;

    bf8 wf[3][2][8];
    #pragma unroll
    for (int g = 0; g < 3; g++)
        #pragma unroll
        for (int u = 0; u < 2; u++) {
            int ct = g * 16 + w * 2 + u;
            #pragma unroll
            for (int kt = 0; kt < 8; kt++)
                wf[g][u][kt] = *(const bf8*)(whh_fr + ((((size_t)n * 48 + ct) * 8 + kt) * 64 + lane) * 8);
        }

    int colb = w * 32 + c16;
    float bn0 = bhh[n * G_ + 512 + colb];
    float bn1 = bhh[n * G_ + 512 + colb + 16];
    float h0 = 0.f, h1 = 0.f;
    if (chunk) {
        const float* hp = h32ws + ((size_t)brow * N_ + n) * H_ + colb;
        h0 = hp[0]; h1 = hp[16];
    }
    hbf[0][q][colb] = f2bf(h0);
    hbf[0][q][colb + 16] = f2bf(h1);

    const unsigned short* ihp = IH + ((size_t)(brow * N_ + n) * TC) * G_ + colb;

    unsigned short c_r0 = ihp[0],   c_r1 = ihp[16];
    unsigned short c_z0 = ihp[256], c_z1 = ihp[272];
    unsigned short c_n0 = ihp[512], c_n1 = ihp[528];
    ihp += G_;

    f4 zf = {0.f, 0.f, 0.f, 0.f};
    __syncthreads();

    #pragma unroll 1
    for (int t = 0; t < TC; t++) {
        const unsigned short* pp = (t + 1 < TC) ? ihp : (ihp - G_);
        unsigned short n_r0 = pp[0],   n_r1 = pp[16];
        unsigned short n_z0 = pp[256], n_z1 = pp[272];
        unsigned short n_n0 = pp[512], n_n1 = pp[528];
        ihp += G_;

        const unsigned short* hb = &hbf[t & 1][0][0];
        f4 acc[3][2];
        #pragma unroll
        for (int g = 0; g < 3; g++)
            #pragma unroll
            for (int u = 0; u < 2; u++) acc[g][u] = zf;
        #pragma unroll
        for (int kt = 0; kt < 8; kt++) {
            bf8 a = *(const bf8*)(hb + hrow * 272 + kt * 32 + q16);
            #pragma unroll
            for (int g = 0; g < 3; g++)
                #pragma unroll
                for (int u = 0; u < 2; u++)
                    acc[g][u] = __builtin_amdgcn_mfma_f32_16x16x32_bf16(a, wf[g][u][kt], acc[g][u], 0, 0, 0);
        }

        float xr0 = bf2f(c_r0) + acc[0][0][0];
        float xz0 = bf2f(c_z0) + acc[1][0][0];
        float rr0 = sigm(xr0), zz0 = sigm(xz0);
        float pre0 = bf2f(c_n0) + rr0 * (acc[2][0][0] + bn0);
        float e20 = __expf(2.f * pre0);
        float nv0 = 1.f - 2.f * __builtin_amdgcn_rcpf(e20 + 1.f);
        float hn0 = nv0 + zz0 * (h0 - nv0);

        float xr1 = bf2f(c_r1) + acc[0][1][0];
        float xz1 = bf2f(c_z1) + acc[1][1][0];
        float rr1 = sigm(xr1), zz1 = sigm(xz1);
        float pre1 = bf2f(c_n1) + rr1 * (acc[2][1][0] + bn1);
        float e21 = __expf(2.f * pre1);
        float nv1 = 1.f - 2.f * __builtin_amdgcn_rcpf(e21 + 1.f);
        float hn1 = nv1 + zz1 * (h1 - nv1);

        h0 = hn0; h1 = hn1;

        unsigned short* hw = &hbf[(t & 1) ^ 1][q][colb];
        hw[0] = f2bf(hn0);
        hw[16] = f2bf(hn1);

        float* op = out + ((size_t)(brow * N_ + n) * T_ + (t0 + t)) * H_ + colb;
        op[0] = hn0;
        op[16] = hn1;

        c_r0 = n_r0; c_r1 = n_r1;
        c_z0 = n_z0; c_z1 = n_z1;
        c_n0 = n_n0; c_n1 = n_n1;

        barrier_lds_only();   // LDS-only wait: IH prefetch + out stores stay in flight
    }

    float* hp = h32ws + ((size_t)brow * N_ + n) * H_ + colb;
    hp[0] = h0;
    hp[16] = h1;
}

extern "C" void kernel_launch(void* const* d_in, const int* in_sizes, int n_in,
                              void* d_out, int out_size, void* d_ws, size_t ws_size,
                              hipStream_t stream) {
    const float* x   = (const float*)d_in[0];
    const float* wih = (const float*)d_in[1];
    const float* whh = (const float*)d_in[2];
    const float* bih = (const float*)d_in[3];
    const float* bhh = (const float*)d_in[4];
    float* out = (float*)d_out;
    unsigned char* ws = (unsigned char*)d_ws;

    if (ws_size < WS_NEEDED) return;

    prep_kernel<<<1024, 256, 0, stream>>>(wih, whh, bih, bhh, ws);
    for (int chunk = 0; chunk < 2; chunk++) {
        int t0 = chunk * TC;
        ih_gemm<<<dim3(256), 1024, 0, stream>>>(x, ws, ws, t0);
        gru_scan<<<dim3(256), 512, 0, stream>>>(ws, ws, bhh, out, chunk, t0);
    }
}

// Round 8
// 271.481 us; speedup vs baseline: 4.1184x; 1.0199x over previous
//
#include <hip/hip_runtime.h>
#include <stdint.h>

#define B_ 64
#define N_ 16
#define T_ 128
#define I_ 256
#define H_ 256
#define G_ 768   // 3*H
#define TC 64    // time chunk

typedef __attribute__((ext_vector_type(8))) short bf8;        // 8 bf16 in 4 VGPRs (MFMA frag)
typedef __attribute__((ext_vector_type(8))) unsigned short u16x8;
typedef __attribute__((ext_vector_type(4))) float f4;

static __device__ __forceinline__ unsigned short f2bf(float f) {
    uint32_t u = __builtin_bit_cast(uint32_t, f);
    u += 0x7fffu + ((u >> 16) & 1u);   // RNE
    return (unsigned short)(u >> 16);
}
static __device__ __forceinline__ float bf2f(unsigned short s) {
    return __builtin_bit_cast(float, ((uint32_t)s) << 16);
}
static __device__ __forceinline__ float sigm(float x) {
    return __builtin_amdgcn_rcpf(1.f + __expf(-x));
}

// Barrier that waits ONLY on LDS ops (lgkmcnt) — does not drain vmcnt, so global
// prefetch loads / output stores stay in flight across the per-step barrier.
static __device__ __forceinline__ void barrier_lds_only() {
    asm volatile("s_waitcnt lgkmcnt(0)\n\ts_barrier" ::: "memory");
}

// ---- ws layout (bytes) ----
// IH relayout (R8): per (b,n) 96KB block of ushort, offset
//   ((rt*48 + ct)*4 + r)*64 + q*16 + c16
// where trow = rt*16 + q*4 + r (t within chunk), g = ct*16 + c16.
// ih epilogue: per (ct,rt,r) store addr = base + lane -> 128B contiguous/wave.
#define OFF_WIH   0ull
#define OFF_WHH   6291456ull
#define OFF_BIAS  12582912ull
#define OFF_H32   12632064ull
#define OFF_IH    13680640ull
#define WS_NEEDED (OFF_IH + 100663296ull)

// ---------------- stage 0: convert/shuffle weights ----------------
__global__ __launch_bounds__(256) void prep_kernel(
        const float* __restrict__ wih, const float* __restrict__ whh,
        const float* __restrict__ bih, const float* __restrict__ bhh,
        unsigned char* ws) {
    unsigned short* wih_fr = (unsigned short*)(ws + OFF_WIH);
    unsigned short* whh_fr = (unsigned short*)(ws + OFF_WHH);
    float* bias_f = (float*)(ws + OFF_BIAS);
    int gid = blockIdx.x * blockDim.x + threadIdx.x;
    int nthr = gridDim.x * blockDim.x;

    // fragment order [n][ct(48)][kt(8)][lane(64)][e(8)]
    //   B-frag: col = ct*16 + (lane&15), k = kt*32 + (lane>>4)*8 + e
    for (int o = gid; o < 393216; o += nthr) {
        int lane = o & 63, kt = (o >> 6) & 7, ct = (o >> 9) % 48, n = o / 24576;
        int gcol = ct * 16 + (lane & 15);
        int k0 = kt * 32 + (lane >> 4) * 8;
        const float* s0 = wih + ((size_t)(n * G_ + gcol)) * I_ + k0;
        const float* s1 = whh + ((size_t)(n * G_ + gcol)) * H_ + k0;
        u16x8 v0, v1;
        #pragma unroll
        for (int e = 0; e < 8; e++) { v0[e] = f2bf(s0[e]); v1[e] = f2bf(s1[e]); }
        *(u16x8*)(wih_fr + (size_t)o * 8) = v0;
        *(u16x8*)(whh_fr + (size_t)o * 8) = v1;
    }
    for (int o = gid; o < N_ * G_; o += nthr) {
        int g = o % G_;
        bias_f[o] = bih[o] + (g < 512 ? bhh[o] : 0.f);
    }
}

// ---------------- stage 1: IH = bf16( x @ wih^T + bias_f ) for one T-chunk ----------------
// grid 256 = 1 block/CU; block = (n, bq) covering 4 b-tiles of 64 rows x 768 cols.
// XCD-aware map: n = (blk&7)*2 + (blk>>7) -> both blocks of an n-pair share an XCD L2.
// R8: epilogue stores to the coalesced IH relayout (128B contiguous per wave-store).
__global__ __launch_bounds__(1024, 1) void ih_gemm(
        const float* __restrict__ x, const unsigned char* __restrict__ wsr,
        unsigned char* ws, int t0) {
    const unsigned short* wih_fr = (const unsigned short*)(wsr + OFF_WIH);
    const float* bias_f = (const float*)(wsr + OFF_BIAS);
    unsigned short* IH = (unsigned short*)(ws + OFF_IH);

    __shared__ __align__(16) unsigned short As[4 * 64 * 256];   // 128 KB

    int tid = threadIdx.x, lane = tid & 63, w = tid >> 6;
    int blk = blockIdx.x;
    int n = (blk & 7) * 2 + (blk >> 7);
    int bq = (blk >> 3) & 15;
    int c16 = lane & 15, q = lane >> 4, q16 = q * 8;

    // stage A: 4 tiles x 64 rows x 256 k (fp32 -> bf16), swizzled
    #pragma unroll
    for (int i = 0; i < 4; i++) {
        int b = bq * 4 + i;
        const float* xb = x + (((size_t)(b * N_ + n)) * T_ + t0) * I_;
        #pragma unroll
        for (int j = 0; j < 2; j++) {
            int chunk = j * 1024 + tid;
            int row = chunk >> 5, kc = chunk & 31;
            const float* s = xb + row * I_ + kc * 8;
            float4 f0 = *(const float4*)s;
            float4 f1 = *(const float4*)(s + 4);
            u16x8 v;
            v[0] = f2bf(f0.x); v[1] = f2bf(f0.y); v[2] = f2bf(f0.z); v[3] = f2bf(f0.w);
            v[4] = f2bf(f1.x); v[5] = f2bf(f1.y); v[6] = f2bf(f1.z); v[7] = f2bf(f1.w);
            int eoff = i * 16384 + row * 256 + ((kc * 8) ^ ((row & 7) << 3));
            *(u16x8*)(As + eoff) = v;
        }
    }
    __syncthreads();

    // wave w owns col-tiles ct = w*3 .. w*3+2
    const unsigned short* bptr = wih_fr + (((size_t)n * 48 + w * 3) * 8) * 64 * 8;
    f4 zf = {0.f, 0.f, 0.f, 0.f};

    #pragma unroll 1
    for (int i = 0; i < 4; i++) {
        int b = bq * 4 + i;
        const unsigned short* Ai = As + i * 16384;

        f4 acc[4][3];
        #pragma unroll
        for (int rt = 0; rt < 4; rt++)
            #pragma unroll
            for (int c = 0; c < 3; c++) acc[rt][c] = zf;

        bf8 bc[3], bn[3];
        #pragma unroll
        for (int c = 0; c < 3; c++)
            bc[c] = *(const bf8*)(bptr + (((size_t)c * 8 + 0) * 64 + lane) * 8);

        #pragma unroll 1
        for (int kt = 0; kt < 8; kt++) {
            int ktn = (kt + 1) & 7;
            #pragma unroll
            for (int c = 0; c < 3; c++)
                bn[c] = *(const bf8*)(bptr + (((size_t)c * 8 + ktn) * 64 + lane) * 8);
            bf8 a[4];
            #pragma unroll
            for (int rt = 0; rt < 4; rt++) {
                int ar = rt * 16 + c16;
                a[rt] = *(const bf8*)(Ai + ar * 256 + ((kt * 32 + q16) ^ ((ar & 7) << 3)));
            }
            #pragma unroll
            for (int c = 0; c < 3; c++)
                #pragma unroll
                for (int rt = 0; rt < 4; rt++)
                    acc[rt][c] = __builtin_amdgcn_mfma_f32_16x16x32_bf16(a[rt], bc[c], acc[rt][c], 0, 0, 0);
            #pragma unroll
            for (int c = 0; c < 3; c++) bc[c] = bn[c];
        }

        // epilogue: +bias, store bf16 to relayout.
        // thread (w,lane) holds g = (w*3+c)*16 + c16, trow = rt*16 + q*4 + r.
        // slot = ((rt*48 + ct)*4 + r)*64 + q*16 + c16 = ((rt*48+ct)*4+r)*64 + lane.
        unsigned short* ob = IH + (size_t)(b * N_ + n) * 49152 + lane;
        #pragma unroll
        for (int c = 0; c < 3; c++) {
            int ct = w * 3 + c;
            float bias = bias_f[n * G_ + ct * 16 + c16];
            #pragma unroll
            for (int rt = 0; rt < 4; rt++) {
                #pragma unroll
                for (int r = 0; r < 4; r++)
                    ob[(((rt * 48 + ct) * 4) + r) * 64] = f2bf(acc[rt][c][r] + bias);
            }
        }
    }
}

// ---------------- stage 2: sequential GRU scan ----------------
// R8: IH reads use the relayout; math unchanged (bit-identical values).
__global__ __launch_bounds__(512, 2) void gru_scan(
        const unsigned char* __restrict__ wsr, unsigned char* ws,
        const float* __restrict__ bhh, float* __restrict__ out,
        int chunk, int t0) {
    const unsigned short* IH = (const unsigned short*)(wsr + OFF_IH);
    const unsigned short* whh_fr = (const unsigned short*)(wsr + OFF_WHH);
    float* h32ws = (float*)(ws + OFF_H32);

    __shared__ __align__(16) unsigned short hbf[2][4][272];

    int tid = threadIdx.x, lane = tid & 63, w = tid >> 6;
    int n = blockIdx.x & 15, rg = blockIdx.x >> 4;

    int c16 = lane & 15;
    int q = lane >> 4;
    int hrow = c16 >> 2;
    int q16 = q * 8;
    int brow = rg * 4 + q;

    bf8 wf[3][2][8];
    #pragma unroll
    for (int g = 0; g < 3; g++)
        #pragma unroll
        for (int u = 0; u < 2; u++) {
            int ct = g * 16 + w * 2 + u;
            #pragma unroll
            for (int kt = 0; kt < 8; kt++)
                wf[g][u][kt] = *(const bf8*)(whh_fr + ((((size_t)n * 48 + ct) * 8 + kt) * 64 + lane) * 8);
        }

    int colb = w * 32 + c16;
    float bn0 = bhh[n * G_ + 512 + colb];
    float bn1 = bhh[n * G_ + 512 + colb + 16];
    float h0 = 0.f, h1 = 0.f;
    if (chunk) {
        const float* hp = h32ws + ((size_t)brow * N_ + n) * H_ + colb;
        h0 = hp[0]; h1 = hp[16];
    }
    hbf[0][q][colb] = f2bf(h0);
    hbf[0][q][colb + 16] = f2bf(h1);

    // relayout read base: + c16; per-step offset tpart(t); per-gate ct offsets.
    const unsigned short* ihb = IH + (size_t)(brow * N_ + n) * 49152 + c16;
    int cb2 = w * 512;   // ct = w*2 -> (w*2)*256

    // tpart(t) = (t>>4)*12288 + (t&3)*64 + ((t>>2)&3)*16
    #define TPART(t) (((t) >> 4) * 12288 + ((t) & 3) * 64 + (((t) >> 2) & 3) * 16)

    {
        const unsigned short* p = ihb + TPART(0) + cb2;
        // loads rotated into c_* below
    }
    unsigned short c_r0, c_r1, c_z0, c_z1, c_n0, c_n1;
    {
        const unsigned short* p = ihb + TPART(0) + cb2;
        c_r0 = p[0];    c_r1 = p[256];
        c_z0 = p[4096]; c_z1 = p[4352];
        c_n0 = p[8192]; c_n1 = p[8448];
    }

    f4 zf = {0.f, 0.f, 0.f, 0.f};
    __syncthreads();

    #pragma unroll 1
    for (int t = 0; t < TC; t++) {
        int tn = (t + 1 < TC) ? (t + 1) : t;
        const unsigned short* p = ihb + TPART(tn) + cb2;
        unsigned short n_r0 = p[0],    n_r1 = p[256];
        unsigned short n_z0 = p[4096], n_z1 = p[4352];
        unsigned short n_n0 = p[8192], n_n1 = p[8448];

        const unsigned short* hb = &hbf[t & 1][0][0];
        f4 acc[3][2];
        #pragma unroll
        for (int g = 0; g < 3; g++)
            #pragma unroll
            for (int u = 0; u < 2; u++) acc[g][u] = zf;
        #pragma unroll
        for (int kt = 0; kt < 8; kt++) {
            bf8 a = *(const bf8*)(hb + hrow * 272 + kt * 32 + q16);
            #pragma unroll
            for (int g = 0; g < 3; g++)
                #pragma unroll
                for (int u = 0; u < 2; u++)
                    acc[g][u] = __builtin_amdgcn_mfma_f32_16x16x32_bf16(a, wf[g][u][kt], acc[g][u], 0, 0, 0);
        }

        float xr0 = bf2f(c_r0) + acc[0][0][0];
        float xz0 = bf2f(c_z0) + acc[1][0][0];
        float rr0 = sigm(xr0), zz0 = sigm(xz0);
        float pre0 = bf2f(c_n0) + rr0 * (acc[2][0][0] + bn0);
        float e20 = __expf(2.f * pre0);
        float nv0 = 1.f - 2.f * __builtin_amdgcn_rcpf(e20 + 1.f);
        float hn0 = nv0 + zz0 * (h0 - nv0);

        float xr1 = bf2f(c_r1) + acc[0][1][0];
        float xz1 = bf2f(c_z1) + acc[1][1][0];
        float rr1 = sigm(xr1), zz1 = sigm(xz1);
        float pre1 = bf2f(c_n1) + rr1 * (acc[2][1][0] + bn1);
        float e21 = __expf(2.f * pre1);
        float nv1 = 1.f - 2.f * __builtin_amdgcn_rcpf(e21 + 1.f);
        float hn1 = nv1 + zz1 * (h1 - nv1);

        h0 = hn0; h1 = hn1;

        unsigned short* hw = &hbf[(t & 1) ^ 1][q][colb];
        hw[0] = f2bf(hn0);
        hw[16] = f2bf(hn1);

        float* op = out + ((size_t)(brow * N_ + n) * T_ + (t0 + t)) * H_ + colb;
        op[0] = hn0;
        op[16] = hn1;

        c_r0 = n_r0; c_r1 = n_r1;
        c_z0 = n_z0; c_z1 = n_z1;
        c_n0 = n_n0; c_n1 = n_n1;

        barrier_lds_only();   // LDS-only wait: IH prefetch + out stores stay in flight
    }

    float* hp = h32ws + ((size_t)brow * N_ + n) * H_ + colb;
    hp[0] = h0;
    hp[16] = h1;
}

extern "C" void kernel_launch(void* const* d_in, const int* in_sizes, int n_in,
                              void* d_out, int out_size, void* d_ws, size_t ws_size,
                              hipStream_t stream) {
    const float* x   = (const float*)d_in[0];
    const float* wih = (const float*)d_in[1];
    const float* whh = (const float*)d_in[2];
    const float* bih = (const float*)d_in[3];
    const float* bhh = (const float*)d_in[4];
    float* out = (float*)d_out;
    unsigned char* ws = (unsigned char*)d_ws;

    if (ws_size < WS_NEEDED) return;

    prep_kernel<<<1024, 256, 0, stream>>>(wih, whh, bih, bhh, ws);
    for (int chunk = 0; chunk < 2; chunk++) {
        int t0 = chunk * TC;
        ih_gemm<<<dim3(256), 1024, 0, stream>>>(x, ws, ws, t0);
        gru_scan<<<dim3(256), 512, 0, stream>>>(ws, ws, bhh, out, chunk, t0);
    }
}